// Round 7
// baseline (106.834 us; speedup 1.0000x reference)
//
#include <hip/hip_runtime.h>
#include <hip/hip_bf16.h>
#include <hip/hip_fp16.h>

// Problem constants
#define NXv 128
#define NYv 128
#define NZv 8
#define NVOX (NXv * NYv * NZv)   // 131072
#define NV 6
#define NC 64
#define HFv 116
#define WFv 200
#define PLANE (HFv * WFv)        // 23200
#define NBLK (NXv * NYv / 8)     // 2048 gather blocks
#define NTILE ((PLANE + 63) / 64 * NV)   // 363*6 = 2178 transpose tiles

// Workspace layout
#define FT_BYTES  ((size_t)NV * PLANE * NC * 2)        // 17,817,600 bf16 feat
#define PD_BYTES  ((size_t)NBLK * 64 * NV * 16)        // 12,582,912 rec slab
#define CNT_BYTES ((size_t)NBLK * 64 * 4)              //    524,288
#define INV_BYTES ((size_t)NBLK * 64 * 4)              //    524,288

typedef float floatx4 __attribute__((ext_vector_type(4)));

// ---- helpers ---------------------------------------------------------------
__device__ inline unsigned int f2bf(float f) {   // f32 -> bf16 bits, RNE
  unsigned int x = __float_as_uint(f);
  unsigned int r = x + 0x7fffu + ((x >> 16) & 1u);
  return (r >> 16) & 0xffffu;
}
__device__ inline float bf_lo(unsigned int q) { return __uint_as_float(q << 16); }
__device__ inline float bf_hi(unsigned int q) { return __uint_as_float(q & 0xffff0000u); }

__device__ inline unsigned short f2h_bits(float f) {
  __half h = __float2half(f);
  return *reinterpret_cast<unsigned short*>(&h);
}
__device__ inline float h_bits2f(unsigned short u) {
  __half_raw r; r.x = u;
  __half h = *reinterpret_cast<__half*>(&r);
  return __half2float(h);
}

// shared geometry: blockIdx -> (ix, iy0g), XCD-aware swizzle (must match in K1/K2)
__device__ inline void block_geom(int bi, int& ix, int& iy0g) {
  const int xcd = bi & 7;
  const int r   = bi >> 3;
  const int tid = xcd * 2 + (r >> 7);
  const int q   = r & 127;
  ix   = (tid & 3) * 32 + (q & 31);
  iy0g = ((tid >> 2) * 4 + (q >> 5)) * 8;
}

// ---------------------------------------------------------------------------
// K1: transpose share + THIS BLOCK'S projections (Phase A) -> ws.
// Transpose is memory-bound; the projection VALU (incl. 2 IEEE divides/task)
// hides in its memory stalls. Grid = 2048 = gather grid.
// rec layout (per valid (slot,view)) — identical to round 6:
//   rec.x = p00 | (v&1)<<15 | p10<<16 | ((v>>1)&1)<<31
//   rec.y = p01 | ((v>>2)&1)<<15 | p11<<16
//   rec.z = f16(w00)|f16(w10)<<16 ; rec.w = f16(w01)|f16(w11)<<16
// p* independently clamped (reference per-tap clip semantics).
// ---------------------------------------------------------------------------
__global__ __launch_bounds__(256, 4) void prep_kernel(
    const float* __restrict__ in,        // x_fov [V][C][PLANE] f32
    unsigned int* __restrict__ feat_out, // [V][PLANE][32] packed bf16x2
    const float* __restrict__ points,
    const float* __restrict__ proj,
    uint4* __restrict__ pdata,           // [NBLK][64*NV]
    unsigned int* __restrict__ cnt_out,  // [NBLK][64]
    float* __restrict__ inv_out) {       // [NBLK][64]
  __shared__ float tile[64][65];
  __shared__ int   cntl[64];
  __shared__ float projl[96];

  const int b = blockIdx.x;
  const int t = threadIdx.x;
  int ix, iy0g;
  block_geom(b, ix, iy0g);

  if (t < 96) projl[t] = proj[t];
  if (t < 64) cntl[t] = 0;
  __syncthreads();

  // ---- Phase A: this block's 64 points x 6 views -> compacted recs in ws ----
  for (int task = t; task < 64 * NV; task += 256) {
    const int slot = task / NV;
    const int v    = task - slot * NV;
    const int j    = slot >> 3;
    const int iz   = slot & 7;
    const int n    = iz * (NXv * NYv) + (iy0g + j) * NXv + ix;

    const float x = points[n * 3 + 0];
    const float y = points[n * 3 + 1];
    const float z = points[n * 3 + 2];

    const float* M = projl + v * 16;
    const float cx = M[0] * x + M[1] * y + M[2]  * z + M[3];
    const float cy = M[4] * x + M[5] * y + M[6]  * z + M[7];
    const float cz = M[8] * x + M[9] * y + M[10] * z + M[11];

    const float dz = (fabsf(cz) > 1e-6f) ? cz : 1e-6f;
    const float u  = cx / dz;
    const float vv = cy / dz;

    const bool valid = (cz > 0.0f) && (u > 0.0f) && (u < 1600.0f) &&
                       (vv > 0.0f) && (vv < 928.0f);
    if (valid) {
      const float px = u  / 1600.0f * 200.0f - 0.5f;
      const float py = vv / 928.0f  * 116.0f - 0.5f;
      const float fx0 = floorf(px);
      const float fy0 = floorf(py);
      const float wx1 = px - fx0;
      const float wy1 = py - fy0;
      const float wx0 = 1.0f - wx1;
      const float wy0 = 1.0f - wy1;
      const int ix0 = (int)fx0;
      const int iy0 = (int)fy0;

      const bool bx0 = (ix0 >= 0) && (ix0 < WFv);
      const bool bx1 = (ix0 + 1 >= 0) && (ix0 + 1 < WFv);
      const bool by0 = (iy0 >= 0) && (iy0 < HFv);
      const bool by1 = (iy0 + 1 >= 0) && (iy0 + 1 < HFv);

      const int xc0 = min(max(ix0, 0), WFv - 1);
      const int xc1 = min(max(ix0 + 1, 0), WFv - 1);
      const int yc0 = min(max(iy0, 0), HFv - 1);
      const int yc1 = min(max(iy0 + 1, 0), HFv - 1);
      const unsigned int p00 = (unsigned int)(yc0 * WFv + xc0);
      const unsigned int p10 = (unsigned int)(yc0 * WFv + xc1);
      const unsigned int p01 = (unsigned int)(yc1 * WFv + xc0);
      const unsigned int p11 = (unsigned int)(yc1 * WFv + xc1);
      const unsigned int uv = (unsigned int)v;

      uint4 rec;
      rec.x = p00 | ((uv & 1u) << 15) | (p10 << 16) | (((uv >> 1) & 1u) << 31);
      rec.y = p01 | (((uv >> 2) & 1u) << 15) | (p11 << 16);
      rec.z = (unsigned int)f2h_bits((bx0 && by0) ? wx0 * wy0 : 0.0f) |
              ((unsigned int)f2h_bits((bx1 && by0) ? wx1 * wy0 : 0.0f) << 16);
      rec.w = (unsigned int)f2h_bits((bx0 && by1) ? wx0 * wy1 : 0.0f) |
              ((unsigned int)f2h_bits((bx1 && by1) ? wx1 * wy1 : 0.0f) << 16);
      const int idx = atomicAdd(&cntl[slot], 1);
      pdata[(size_t)b * (64 * NV) + slot * NV + idx] = rec;
    }
  }
  __syncthreads();
  if (t < 64) {
    const int c = cntl[t];
    cnt_out[(size_t)b * 64 + t] = (unsigned int)c;
    inv_out[(size_t)b * 64 + t] = (c > 0) ? 1.0f / (float)c : 0.0f;
  }

  // ---- Phase T: transpose share (tiles b, b+2048) ----
  for (int tl = b; tl < NTILE; tl += NBLK) {
    const int v  = tl / 363;
    const int p0 = (tl - v * 363) * 64;
    const float* src = in + (size_t)v * NC * PLANE;
    unsigned int* dst = feat_out + (size_t)v * PLANE * (NC / 2);

    __syncthreads();   // tile reuse across loop iterations
#pragma unroll
    for (int i = 0; i < 4; ++i) {
      const int idx = i * 256 + t;
      const int c  = idx >> 4;
      const int p4 = idx & 15;
      const int pp = p0 + p4 * 4;
      if (pp < PLANE) {   // PLANE%4==0 -> full float4 ok
        const floatx4 f = __builtin_nontemporal_load(
            (const floatx4*)(src + (size_t)c * PLANE + pp));
        tile[p4 * 4 + 0][c] = f.x;
        tile[p4 * 4 + 1][c] = f.y;
        tile[p4 * 4 + 2][c] = f.z;
        tile[p4 * 4 + 3][c] = f.w;
      }
    }
    __syncthreads();
#pragma unroll
    for (int i = 0; i < 2; ++i) {
      const int idx = i * 256 + t;
      const int p   = idx >> 3;
      const int c8  = idx & 7;
      const int pp  = p0 + p;
      if (pp < PLANE) {
        uint4 w;
        w.x = f2bf(tile[p][c8 * 8 + 0]) | (f2bf(tile[p][c8 * 8 + 1]) << 16);
        w.y = f2bf(tile[p][c8 * 8 + 2]) | (f2bf(tile[p][c8 * 8 + 3]) << 16);
        w.z = f2bf(tile[p][c8 * 8 + 4]) | (f2bf(tile[p][c8 * 8 + 5]) << 16);
        w.w = f2bf(tile[p][c8 * 8 + 6]) | (f2bf(tile[p][c8 * 8 + 7]) << 16);
        *(uint4*)(dst + (size_t)pp * 32 + c8 * 4) = w;
      }
    }
  }
}

// ---------------------------------------------------------------------------
// K2: stage recs -> taps -> LDS-transposed nontemporal store.
// 8 points/wave, lane=(point:3,chunk:3); tap = dwordx4 (8 bf16x2 channels).
// ---------------------------------------------------------------------------
__global__ __launch_bounds__(256, 8) void gather_kernel(
    const uint4* __restrict__ feat4,    // [V*PLANE][8] uint4
    const uint4* __restrict__ pdata,    // [NBLK][64*NV]
    const unsigned int* __restrict__ cntg,
    const float* __restrict__ invg,
    float* __restrict__ out) {
  __shared__ unsigned short tile_h[64][66];
  __shared__ uint4 pdl[64 * NV];
  __shared__ int   cntl[64];
  __shared__ float invl[64];

  const int b = blockIdx.x;
  const int t = threadIdx.x;
  int ix, iy0g;
  block_geom(b, ix, iy0g);

  const int lane = t & 63;
  const int wave = t >> 6;

  {
    const uint4* src = pdata + (size_t)b * (64 * NV);
    for (int i = t; i < 64 * NV; i += 256) pdl[i] = src[i];
    if (t < 64) {
      cntl[t] = (int)cntg[(size_t)b * 64 + t];
      invl[t] = invg[(size_t)b * 64 + t];
    }
  }
  __syncthreads();

  const int pg = lane >> 3;    // point within group of 8
  const int ch = lane & 7;     // uint4 chunk (8 channels)

#pragma unroll
  for (int it = 0; it < 2; ++it) {
    const int sl = wave * 16 + it * 8 + pg;
    const int mycnt = cntl[sl];
    int km = mycnt;
    km = max(km, __shfl_xor(km, 8));
    km = max(km, __shfl_xor(km, 16));
    km = max(km, __shfl_xor(km, 32));

    float acc[8];
#pragma unroll
    for (int j2 = 0; j2 < 8; ++j2) acc[j2] = 0.0f;

    for (int k = 0; k < km; ++k) {
      if (k < mycnt) {
        const uint4 rec = pdl[sl * NV + k];
        const unsigned int p00 = rec.x & 0x7fffu;
        const unsigned int p10 = (rec.x >> 16) & 0x7fffu;
        const unsigned int p01 = rec.y & 0x7fffu;
        const unsigned int p11 = (rec.y >> 16) & 0x7fffu;
        const unsigned int v = ((rec.x >> 15) & 1u) | (((rec.x >> 31) & 1u) << 1) |
                               (((rec.y >> 15) & 1u) << 2);
        const float w0 = h_bits2f((unsigned short)(rec.z & 0xffffu));
        const float w1 = h_bits2f((unsigned short)(rec.z >> 16));
        const float w2 = h_bits2f((unsigned short)(rec.w & 0xffffu));
        const float w3 = h_bits2f((unsigned short)(rec.w >> 16));

        const uint4* fb = feat4 + (size_t)v * PLANE * 8 + ch;
        const uint4 q0 = fb[(size_t)p00 * 8];
        const uint4 q1 = fb[(size_t)p10 * 8];
        const uint4 q2 = fb[(size_t)p01 * 8];
        const uint4 q3 = fb[(size_t)p11 * 8];

        acc[0] = fmaf(w0, bf_lo(q0.x), acc[0]); acc[1] = fmaf(w0, bf_hi(q0.x), acc[1]);
        acc[2] = fmaf(w0, bf_lo(q0.y), acc[2]); acc[3] = fmaf(w0, bf_hi(q0.y), acc[3]);
        acc[4] = fmaf(w0, bf_lo(q0.z), acc[4]); acc[5] = fmaf(w0, bf_hi(q0.z), acc[5]);
        acc[6] = fmaf(w0, bf_lo(q0.w), acc[6]); acc[7] = fmaf(w0, bf_hi(q0.w), acc[7]);

        acc[0] = fmaf(w1, bf_lo(q1.x), acc[0]); acc[1] = fmaf(w1, bf_hi(q1.x), acc[1]);
        acc[2] = fmaf(w1, bf_lo(q1.y), acc[2]); acc[3] = fmaf(w1, bf_hi(q1.y), acc[3]);
        acc[4] = fmaf(w1, bf_lo(q1.z), acc[4]); acc[5] = fmaf(w1, bf_hi(q1.z), acc[5]);
        acc[6] = fmaf(w1, bf_lo(q1.w), acc[6]); acc[7] = fmaf(w1, bf_hi(q1.w), acc[7]);

        acc[0] = fmaf(w2, bf_lo(q2.x), acc[0]); acc[1] = fmaf(w2, bf_hi(q2.x), acc[1]);
        acc[2] = fmaf(w2, bf_lo(q2.y), acc[2]); acc[3] = fmaf(w2, bf_hi(q2.y), acc[3]);
        acc[4] = fmaf(w2, bf_lo(q2.z), acc[4]); acc[5] = fmaf(w2, bf_hi(q2.z), acc[5]);
        acc[6] = fmaf(w2, bf_lo(q2.w), acc[6]); acc[7] = fmaf(w2, bf_hi(q2.w), acc[7]);

        acc[0] = fmaf(w3, bf_lo(q3.x), acc[0]); acc[1] = fmaf(w3, bf_hi(q3.x), acc[1]);
        acc[2] = fmaf(w3, bf_lo(q3.y), acc[2]); acc[3] = fmaf(w3, bf_hi(q3.y), acc[3]);
        acc[4] = fmaf(w3, bf_lo(q3.z), acc[4]); acc[5] = fmaf(w3, bf_hi(q3.z), acc[5]);
        acc[6] = fmaf(w3, bf_lo(q3.w), acc[6]); acc[7] = fmaf(w3, bf_hi(q3.w), acc[7]);
      }
    }

    const float inv = invl[sl];
#pragma unroll
    for (int j2 = 0; j2 < 4; ++j2) {
      const unsigned int pk =
          (unsigned int)f2h_bits(acc[j2 * 2 + 0] * inv) |
          ((unsigned int)f2h_bits(acc[j2 * 2 + 1] * inv) << 16);
      *(unsigned int*)&tile_h[sl][ch * 8 + j2 * 2] = pk;
    }
  }

  __syncthreads();

  const size_t obase = (size_t)ix * (NYv * NZv) + (size_t)iy0g * NZv + lane;
#pragma unroll
  for (int i = 0; i < 16; ++i) {
    const int c = i * 4 + wave;
    const float val = h_bits2f(tile_h[lane][c]);
    __builtin_nontemporal_store(val, &out[(size_t)c * NVOX + obase]);
  }
}

// ---------------------------------------------------------------------------
// Fallback: direct channel-major sampling (no workspace).
// ---------------------------------------------------------------------------
__global__ __launch_bounds__(256) void sample_fallback(
    const float* __restrict__ feat,
    const float* __restrict__ points,
    const float* __restrict__ proj,
    float* __restrict__ out) {
  const int wave = threadIdx.x >> 6;
  const int lane = threadIdx.x & 63;
  const int n = blockIdx.x * 4 + wave;

  const float x = points[n * 3 + 0];
  const float y = points[n * 3 + 1];
  const float z = points[n * 3 + 2];

  float acc = 0.0f;
  int cnt = 0;

#pragma unroll
  for (int v = 0; v < NV; ++v) {
    const float* M = proj + v * 16;
    const float cx = M[0] * x + M[1] * y + M[2]  * z + M[3];
    const float cy = M[4] * x + M[5] * y + M[6]  * z + M[7];
    const float cz = M[8] * x + M[9] * y + M[10] * z + M[11];
    const float dz = (fabsf(cz) > 1e-6f) ? cz : 1e-6f;
    const float u  = cx / dz;
    const float vv = cy / dz;
    const bool valid = (cz > 0.0f) && (u > 0.0f) && (u < 1600.0f) &&
                       (vv > 0.0f) && (vv < 928.0f);
    if (!valid) continue;
    cnt++;
    const float px = u  / 1600.0f * 200.0f - 0.5f;
    const float py = vv / 928.0f  * 116.0f - 0.5f;
    const float fx0 = floorf(px);
    const float fy0 = floorf(py);
    const float wx1 = px - fx0;
    const float wy1 = py - fy0;
    const float wx0 = 1.0f - wx1;
    const float wy0 = 1.0f - wy1;
    const int ix0 = (int)fx0;
    const int iy0 = (int)fy0;
    const float w00 = wx0 * wy0, w10 = wx1 * wy0, w01 = wx0 * wy1, w11 = wx1 * wy1;
    const float* basev = feat + ((size_t)v * NC + lane) * PLANE;
    auto tap = [&](int xi, int yi, float w) {
      if (xi >= 0 && xi < WFv && yi >= 0 && yi < HFv)
        acc += w * basev[yi * WFv + xi];
    };
    tap(ix0,     iy0,     w00);
    tap(ix0 + 1, iy0,     w10);
    tap(ix0,     iy0 + 1, w01);
    tap(ix0 + 1, iy0 + 1, w11);
  }

  const float scale = (cnt > 0) ? (1.0f / (float)cnt) : 0.0f;
  const int iz  = n >> 14;
  const int rem = n & 16383;
  const int iy  = rem >> 7;
  const int ixx = rem & 127;
  out[(((size_t)lane * NXv + ixx) * NYv + iy) * NZv + iz] = acc * scale;
}

extern "C" void kernel_launch(void* const* d_in, const int* in_sizes, int n_in,
                              void* d_out, int out_size, void* d_ws, size_t ws_size,
                              hipStream_t stream) {
  const float* x_fov  = (const float*)d_in[0];  // [1,6,64,116,200] f32
  const float* points = (const float*)d_in[1];  // [131072,3] f32
  const float* proj   = (const float*)d_in[2];  // [6,4,4] f32
  float* out = (float*)d_out;                   // [1,64,128,128,8] f32

  const size_t need = FT_BYTES + PD_BYTES + CNT_BYTES + INV_BYTES;
  if (ws_size >= need) {
    unsigned int* ft = (unsigned int*)d_ws;
    uint4* pd = (uint4*)((char*)d_ws + FT_BYTES);
    unsigned int* cg = (unsigned int*)((char*)d_ws + FT_BYTES + PD_BYTES);
    float* ig = (float*)((char*)d_ws + FT_BYTES + PD_BYTES + CNT_BYTES);

    prep_kernel<<<NBLK, 256, 0, stream>>>(x_fov, ft, points, proj, pd, cg, ig);
    gather_kernel<<<NBLK, 256, 0, stream>>>((const uint4*)ft, pd, cg, ig, out);
  } else {
    sample_fallback<<<NVOX / 4, 256, 0, stream>>>(x_fov, points, proj, out);
  }
}

// Round 9
// 103.493 us; speedup vs baseline: 1.0323x; 1.0323x over previous
//
#include <hip/hip_runtime.h>
#include <hip/hip_bf16.h>
#include <hip/hip_fp16.h>

// Problem constants
#define NXv 128
#define NYv 128
#define NZv 8
#define NVOX (NXv * NYv * NZv)   // 131072
#define NV 6
#define NC 64
#define HFv 116
#define WFv 200
#define PLANE (HFv * WFv)        // 23200

#define FT_BYTES ((size_t)NV * PLANE * NC * 2)   // 17,817,600 (bf16 channels-last)

typedef float floatx4 __attribute__((ext_vector_type(4)));

// ---- helpers ---------------------------------------------------------------
__device__ inline unsigned int f2bf(float f) {   // f32 -> bf16 bits, RNE
  unsigned int x = __float_as_uint(f);
  unsigned int r = x + 0x7fffu + ((x >> 16) & 1u);
  return (r >> 16) & 0xffffu;
}
__device__ inline float bf_lo(unsigned int q) { return __uint_as_float(q << 16); }
__device__ inline float bf_hi(unsigned int q) { return __uint_as_float(q & 0xffff0000u); }

__device__ inline unsigned short f2h_bits(float f) {
  __half h = __float2half(f);
  return *reinterpret_cast<unsigned short*>(&h);
}
__device__ inline float h_bits2f(unsigned short u) {
  __half_raw r; r.x = u;
  __half h = *reinterpret_cast<__half*>(&r);
  return __half2float(h);
}

// ---------------------------------------------------------------------------
// K1: Transpose+convert [V][C][PLANE] f32 -> [V][PLANE][C] bf16 (packed).
// Nontemporal reads (x_fov is read-once; don't evict feat from L2).
// ---------------------------------------------------------------------------
__global__ __launch_bounds__(256) void transpose_feat_bf16(
    const float* __restrict__ in, unsigned int* __restrict__ out32) {
  __shared__ float tile[64][65];                 // [pixel][channel]
  const int v  = blockIdx.y;
  const int p0 = blockIdx.x * 64;
  const float* src = in + (size_t)v * NC * PLANE;
  unsigned int* dst = out32 + (size_t)v * PLANE * (NC / 2);
  const int t = threadIdx.x;

#pragma unroll
  for (int i = 0; i < 4; ++i) {
    const int idx = i * 256 + t;
    const int c  = idx >> 4;
    const int p4 = idx & 15;
    const int pp = p0 + p4 * 4;
    if (pp < PLANE) {                            // PLANE%4==0 -> full float4 ok
      const floatx4 f = __builtin_nontemporal_load(
          (const floatx4*)(src + (size_t)c * PLANE + pp));
      tile[p4 * 4 + 0][c] = f.x;
      tile[p4 * 4 + 1][c] = f.y;
      tile[p4 * 4 + 2][c] = f.z;
      tile[p4 * 4 + 3][c] = f.w;
    }
  }
  __syncthreads();

#pragma unroll
  for (int i = 0; i < 2; ++i) {
    const int idx = i * 256 + t;
    const int p   = idx >> 3;
    const int c8  = idx & 7;
    const int pp  = p0 + p;
    if (pp < PLANE) {
      uint4 w;
      w.x = f2bf(tile[p][c8 * 8 + 0]) | (f2bf(tile[p][c8 * 8 + 1]) << 16);
      w.y = f2bf(tile[p][c8 * 8 + 2]) | (f2bf(tile[p][c8 * 8 + 3]) << 16);
      w.z = f2bf(tile[p][c8 * 8 + 4]) | (f2bf(tile[p][c8 * 8 + 5]) << 16);
      w.w = f2bf(tile[p][c8 * 8 + 6]) | (f2bf(tile[p][c8 * 8 + 7]) << 16);
      *(uint4*)(dst + (size_t)pp * 32 + c8 * 4) = w;
    }
  }
}

// ---------------------------------------------------------------------------
// K2: Fused projection + gather + coalesced store (round-6 structure).
// rec layout (per valid (slot,view)):
//   rec.x = p00 | (v&1)<<15 | p10<<16 | ((v>>1)&1)<<31
//   rec.y = p01 | ((v>>2)&1)<<15 | p11<<16
//   rec.z = f16(w00)|f16(w10)<<16 ; rec.w = f16(w01)|f16(w11)<<16
// p* independently clamped (reference per-tap clip semantics).
// ---------------------------------------------------------------------------
__global__ __launch_bounds__(256, 8) void gather_fused(
    const uint4* __restrict__ feat4,    // [V*PLANE][8] uint4 (64 bf16 ch)
    const float* __restrict__ points,
    const float* __restrict__ proj,
    float* __restrict__ out) {
  __shared__ unsigned short tile_h[64][66];   // f16 staging, 8.4KB
  __shared__ uint4 pdl[64 * NV];              // 6KB
  __shared__ int   cntl[64];
  __shared__ float invl[64];
  __shared__ float projl[96];
  __shared__ float ptx[64], pty[64], ptz[64]; // staged points (1x, not 6x)

  // spatial swizzle: XCD (~bi&7) owns two 32ix x 32iy squares
  const int bi   = blockIdx.x;
  const int xcd  = bi & 7;
  const int r    = bi >> 3;
  const int tid  = xcd * 2 + (r >> 7);
  const int q    = r & 127;
  const int ix   = (tid & 3) * 32 + (q & 31);
  const int iyg  = (tid >> 2) * 4 + (q >> 5);
  const int iy0g = iyg * 8;

  const int t    = threadIdx.x;
  const int lane = t & 63;
  const int wave = t >> 6;

  if (t < 96) projl[t] = proj[t];
  if (t < 64) {
    cntl[t] = 0;
    const int j  = t >> 3;
    const int iz = t & 7;
    const int n  = iz * (NXv * NYv) + (iy0g + j) * NXv + ix;
    ptx[t] = points[n * 3 + 0];
    pty[t] = points[n * 3 + 1];
    ptz[t] = points[n * 3 + 2];
  }
  __syncthreads();

  // ---- Phase A: projections, compacted per slot ----
  for (int task = t; task < 64 * NV; task += 256) {
    const int slot = task / NV;
    const int v    = task - slot * NV;

    const float x = ptx[slot];   // LDS broadcast (6 consecutive threads share)
    const float y = pty[slot];
    const float z = ptz[slot];

    const float* M = projl + v * 16;
    const float cx = M[0] * x + M[1] * y + M[2]  * z + M[3];
    const float cy = M[4] * x + M[5] * y + M[6]  * z + M[7];
    const float cz = M[8] * x + M[9] * y + M[10] * z + M[11];

    const float dz = (fabsf(cz) > 1e-6f) ? cz : 1e-6f;
    const float u  = cx / dz;
    const float vv = cy / dz;

    const bool valid = (cz > 0.0f) && (u > 0.0f) && (u < 1600.0f) &&
                       (vv > 0.0f) && (vv < 928.0f);
    if (valid) {
      const float px = u  / 1600.0f * 200.0f - 0.5f;
      const float py = vv / 928.0f  * 116.0f - 0.5f;
      const float fx0 = floorf(px);
      const float fy0 = floorf(py);
      const float wx1 = px - fx0;
      const float wy1 = py - fy0;
      const float wx0 = 1.0f - wx1;
      const float wy0 = 1.0f - wy1;
      const int ix0 = (int)fx0;
      const int iy0 = (int)fy0;

      // per-tap in-bounds masks (reference semantics)
      const bool bx0 = (ix0 >= 0) && (ix0 < WFv);
      const bool bx1 = (ix0 + 1 >= 0) && (ix0 + 1 < WFv);
      const bool by0 = (iy0 >= 0) && (iy0 < HFv);
      const bool by1 = (iy0 + 1 >= 0) && (iy0 + 1 < HFv);

      // per-tap independently clamped coords (reference semantics)
      const int xc0 = min(max(ix0, 0), WFv - 1);
      const int xc1 = min(max(ix0 + 1, 0), WFv - 1);
      const int yc0 = min(max(iy0, 0), HFv - 1);
      const int yc1 = min(max(iy0 + 1, 0), HFv - 1);
      const unsigned int p00 = (unsigned int)(yc0 * WFv + xc0);
      const unsigned int p10 = (unsigned int)(yc0 * WFv + xc1);
      const unsigned int p01 = (unsigned int)(yc1 * WFv + xc0);
      const unsigned int p11 = (unsigned int)(yc1 * WFv + xc1);
      const unsigned int uv = (unsigned int)v;

      uint4 rec;
      rec.x = p00 | ((uv & 1u) << 15) | (p10 << 16) | (((uv >> 1) & 1u) << 31);
      rec.y = p01 | (((uv >> 2) & 1u) << 15) | (p11 << 16);
      rec.z = (unsigned int)f2h_bits((bx0 && by0) ? wx0 * wy0 : 0.0f) |
              ((unsigned int)f2h_bits((bx1 && by0) ? wx1 * wy0 : 0.0f) << 16);
      rec.w = (unsigned int)f2h_bits((bx0 && by1) ? wx0 * wy1 : 0.0f) |
              ((unsigned int)f2h_bits((bx1 && by1) ? wx1 * wy1 : 0.0f) << 16);
      const int idx = atomicAdd(&cntl[slot], 1);
      pdl[slot * NV + idx] = rec;
    }
  }
  __syncthreads();
  if (t < 64) { const int c = cntl[t]; invl[t] = (c > 0) ? 1.0f / (float)c : 0.0f; }
  __syncthreads();

  // ---- Phase B: taps over compacted valid views ----
  const int pg = lane >> 3;    // point within group of 8
  const int ch = lane & 7;     // uint4 chunk (8 channels)

#pragma unroll
  for (int it = 0; it < 2; ++it) {
    const int sl = wave * 16 + it * 8 + pg;
    const int mycnt = cntl[sl];
    int km = mycnt;
    km = max(km, __shfl_xor(km, 8));
    km = max(km, __shfl_xor(km, 16));
    km = max(km, __shfl_xor(km, 32));   // wave-uniform max over the 8 points

    float acc[8];
#pragma unroll
    for (int j2 = 0; j2 < 8; ++j2) acc[j2] = 0.0f;

    for (int k = 0; k < km; ++k) {
      if (k < mycnt) {
        const uint4 rec = pdl[sl * NV + k];
        const unsigned int p00 = rec.x & 0x7fffu;
        const unsigned int p10 = (rec.x >> 16) & 0x7fffu;
        const unsigned int p01 = rec.y & 0x7fffu;
        const unsigned int p11 = (rec.y >> 16) & 0x7fffu;
        const unsigned int v = ((rec.x >> 15) & 1u) | (((rec.x >> 31) & 1u) << 1) |
                               (((rec.y >> 15) & 1u) << 2);
        const float w0 = h_bits2f((unsigned short)(rec.z & 0xffffu));
        const float w1 = h_bits2f((unsigned short)(rec.z >> 16));
        const float w2 = h_bits2f((unsigned short)(rec.w & 0xffffu));
        const float w3 = h_bits2f((unsigned short)(rec.w >> 16));

        const uint4* fb = feat4 + (size_t)v * PLANE * 8 + ch;
        const uint4 q0 = fb[(size_t)p00 * 8];
        const uint4 q1 = fb[(size_t)p10 * 8];
        const uint4 q2 = fb[(size_t)p01 * 8];
        const uint4 q3 = fb[(size_t)p11 * 8];

        acc[0] = fmaf(w0, bf_lo(q0.x), acc[0]); acc[1] = fmaf(w0, bf_hi(q0.x), acc[1]);
        acc[2] = fmaf(w0, bf_lo(q0.y), acc[2]); acc[3] = fmaf(w0, bf_hi(q0.y), acc[3]);
        acc[4] = fmaf(w0, bf_lo(q0.z), acc[4]); acc[5] = fmaf(w0, bf_hi(q0.z), acc[5]);
        acc[6] = fmaf(w0, bf_lo(q0.w), acc[6]); acc[7] = fmaf(w0, bf_hi(q0.w), acc[7]);

        acc[0] = fmaf(w1, bf_lo(q1.x), acc[0]); acc[1] = fmaf(w1, bf_hi(q1.x), acc[1]);
        acc[2] = fmaf(w1, bf_lo(q1.y), acc[2]); acc[3] = fmaf(w1, bf_hi(q1.y), acc[3]);
        acc[4] = fmaf(w1, bf_lo(q1.z), acc[4]); acc[5] = fmaf(w1, bf_hi(q1.z), acc[5]);
        acc[6] = fmaf(w1, bf_lo(q1.w), acc[6]); acc[7] = fmaf(w1, bf_hi(q1.w), acc[7]);

        acc[0] = fmaf(w2, bf_lo(q2.x), acc[0]); acc[1] = fmaf(w2, bf_hi(q2.x), acc[1]);
        acc[2] = fmaf(w2, bf_lo(q2.y), acc[2]); acc[3] = fmaf(w2, bf_hi(q2.y), acc[3]);
        acc[4] = fmaf(w2, bf_lo(q2.z), acc[4]); acc[5] = fmaf(w2, bf_hi(q2.z), acc[5]);
        acc[6] = fmaf(w2, bf_lo(q2.w), acc[6]); acc[7] = fmaf(w2, bf_hi(q2.w), acc[7]);

        acc[0] = fmaf(w3, bf_lo(q3.x), acc[0]); acc[1] = fmaf(w3, bf_hi(q3.x), acc[1]);
        acc[2] = fmaf(w3, bf_lo(q3.y), acc[2]); acc[3] = fmaf(w3, bf_hi(q3.y), acc[3]);
        acc[4] = fmaf(w3, bf_lo(q3.z), acc[4]); acc[5] = fmaf(w3, bf_hi(q3.z), acc[5]);
        acc[6] = fmaf(w3, bf_lo(q3.w), acc[6]); acc[7] = fmaf(w3, bf_hi(q3.w), acc[7]);
      }
    }

    const float inv = invl[sl];
#pragma unroll
    for (int j2 = 0; j2 < 4; ++j2) {
      const unsigned int pk =
          (unsigned int)f2h_bits(acc[j2 * 2 + 0] * inv) |
          ((unsigned int)f2h_bits(acc[j2 * 2 + 1] * inv) << 16);
      *(unsigned int*)&tile_h[sl][ch * 8 + j2 * 2] = pk;
    }
  }

  __syncthreads();

  // ---- Phase C: floatx4 nontemporal coalesced store ----
  // lane = (quad:4, coff:2): 4 consecutive voxels of one channel per store.
  const int qd = lane >> 2;          // voxel quad 0..15
  const int co = lane & 3;           // channel offset 0..3
  const size_t obase = (size_t)ix * (NYv * NZv) + (size_t)iy0g * NZv + qd * 4;
#pragma unroll
  for (int i = 0; i < 4; ++i) {
    const int c = wave * 16 + i * 4 + co;
    floatx4 val;
    val.x = h_bits2f(tile_h[qd * 4 + 0][c]);
    val.y = h_bits2f(tile_h[qd * 4 + 1][c]);
    val.z = h_bits2f(tile_h[qd * 4 + 2][c]);
    val.w = h_bits2f(tile_h[qd * 4 + 3][c]);
    __builtin_nontemporal_store(val, (floatx4*)(out + (size_t)c * NVOX + obase));
  }
}

// ---------------------------------------------------------------------------
// Fallback: direct channel-major sampling (no workspace).
// ---------------------------------------------------------------------------
__global__ __launch_bounds__(256) void sample_fallback(
    const float* __restrict__ feat,
    const float* __restrict__ points,
    const float* __restrict__ proj,
    float* __restrict__ out) {
  const int wave = threadIdx.x >> 6;
  const int lane = threadIdx.x & 63;
  const int n = blockIdx.x * 4 + wave;

  const float x = points[n * 3 + 0];
  const float y = points[n * 3 + 1];
  const float z = points[n * 3 + 2];

  float acc = 0.0f;
  int cnt = 0;

#pragma unroll
  for (int v = 0; v < NV; ++v) {
    const float* M = proj + v * 16;
    const float cx = M[0] * x + M[1] * y + M[2]  * z + M[3];
    const float cy = M[4] * x + M[5] * y + M[6]  * z + M[7];
    const float cz = M[8] * x + M[9] * y + M[10] * z + M[11];
    const float dz = (fabsf(cz) > 1e-6f) ? cz : 1e-6f;
    const float u  = cx / dz;
    const float vv = cy / dz;
    const bool valid = (cz > 0.0f) && (u > 0.0f) && (u < 1600.0f) &&
                       (vv > 0.0f) && (vv < 928.0f);
    if (!valid) continue;
    cnt++;
    const float px = u  / 1600.0f * 200.0f - 0.5f;
    const float py = vv / 928.0f  * 116.0f - 0.5f;
    const float fx0 = floorf(px);
    const float fy0 = floorf(py);
    const float wx1 = px - fx0;
    const float wy1 = py - fy0;
    const float wx0 = 1.0f - wx1;
    const float wy0 = 1.0f - wy1;
    const int ix0 = (int)fx0;
    const int iy0 = (int)fy0;
    const float w00 = wx0 * wy0, w10 = wx1 * wy0, w01 = wx0 * wy1, w11 = wx1 * wy1;
    const float* basev = feat + ((size_t)v * NC + lane) * PLANE;
    auto tap = [&](int xi, int yi, float w) {
      if (xi >= 0 && xi < WFv && yi >= 0 && yi < HFv)
        acc += w * basev[yi * WFv + xi];
    };
    tap(ix0,     iy0,     w00);
    tap(ix0 + 1, iy0,     w10);
    tap(ix0,     iy0 + 1, w01);
    tap(ix0 + 1, iy0 + 1, w11);
  }

  const float scale = (cnt > 0) ? (1.0f / (float)cnt) : 0.0f;
  const int iz  = n >> 14;
  const int rem = n & 16383;
  const int iy  = rem >> 7;
  const int ixx = rem & 127;
  out[(((size_t)lane * NXv + ixx) * NYv + iy) * NZv + iz] = acc * scale;
}

extern "C" void kernel_launch(void* const* d_in, const int* in_sizes, int n_in,
                              void* d_out, int out_size, void* d_ws, size_t ws_size,
                              hipStream_t stream) {
  const float* x_fov  = (const float*)d_in[0];  // [1,6,64,116,200] f32
  const float* points = (const float*)d_in[1];  // [131072,3] f32
  const float* proj   = (const float*)d_in[2];  // [6,4,4] f32
  float* out = (float*)d_out;                   // [1,64,128,128,8] f32

  if (ws_size >= FT_BYTES) {
    unsigned int* ft = (unsigned int*)d_ws;
    dim3 tgrid((PLANE + 63) / 64, NV);
    transpose_feat_bf16<<<tgrid, 256, 0, stream>>>(x_fov, ft);
    gather_fused<<<NXv * NYv / 8, 256, 0, stream>>>((const uint4*)ft, points, proj, out);
  } else {
    sample_fallback<<<NVOX / 4, 256, 0, stream>>>(x_fov, points, proj, out);
  }
}